// Round 3
// baseline (14343.114 us; speedup 1.0000x reference)
//
#include <hip/hip_runtime.h>
#include <cstdint>
#include <cstddef>

#define B_SZ 32
#define NPTS 16384
#define NSAMP 2048
#define F_IN 64
#define C_IN 67
#define D_OUT 128

#define NBLK 8                 // blocks per batch
#define FPS_BLOCK 512          // threads per block
#define PPT 4                  // NPTS / (NBLK * FPS_BLOCK)
#define PTS_PER_BLK (NPTS / NBLK)   // 2048

// ---------------------------------------------------------------------------
// Multi-CU FPS. Grid = 256 blocks (8 per batch), mapped so one batch's blocks
// share an XCD: blockIdx = sub*32 + b. Each thread owns 4 points in regs.
// Per iteration: local dist update + argmax -> wave butterfly -> block reduce
// -> global combine via device-scope atomicMax on packed u64 key
// (dist_bits<<32 | ~idx  => max dist, tie -> lowest index, = jnp.argmax),
// release-inc of an arrival counter, acquire spin until all NBLK arrived.
// Distance math: explicit rn ops, no FMA (bit-matches reference; absmax 0
// in round 1 with identical arithmetic).
// ---------------------------------------------------------------------------
__global__ __launch_bounds__(FPS_BLOCK, 2)
void fps_kernel(const float* __restrict__ xyz,        // [B, N, 3]
                const int* __restrict__ init_far,     // [B]
                int* __restrict__ idx_out,            // [B, S]
                float* __restrict__ newxyz_out,       // [B, S, 3]
                unsigned long long* __restrict__ gkey,// [B, S] zeroed
                unsigned int* __restrict__ gcnt)      // [B, S] zeroed
{
    const int blk = blockIdx.x;
    const int b   = blk & 31;
    const int sub = blk >> 5;
    const int tid = threadIdx.x;
    const float* base = xyz + (size_t)b * NPTS * 3;

    // this thread's 4 points: global idx = sub*2048 + p*512 + tid (asc. in p)
    const int p0 = sub * PTS_PER_BLK + tid;
    float px[PPT], py[PPT], pz[PPT], dist[PPT];
#pragma unroll
    for (int p = 0; p < PPT; ++p) {
        const int i = p0 + p * FPS_BLOCK;
        px[p] = base[i * 3 + 0];
        py[p] = base[i * 3 + 1];
        pz[p] = base[i * 3 + 2];
        dist[p] = 1e10f;
    }

    __shared__ float s_wval[FPS_BLOCK / 64];
    __shared__ int   s_widx[FPS_BLOCK / 64];
    __shared__ float s_cx, s_cy, s_cz;
    __shared__ int   s_fidx;

    int cur = init_far[b];
    float cx = base[cur * 3 + 0];
    float cy = base[cur * 3 + 1];
    float cz = base[cur * 3 + 2];

    unsigned long long* mykey = gkey + (size_t)b * NSAMP;
    unsigned int*       mycnt = gcnt + (size_t)b * NSAMP;

    const int lane = tid & 63;
    const int wave = tid >> 6;

    for (int s = 0; s < NSAMP; ++s) {
        // record BEFORE update (reference scan semantics)
        if (sub == 0 && tid == 0) {
            idx_out[b * NSAMP + s] = cur;
            float* o = newxyz_out + (size_t)(b * NSAMP + s) * 3;
            o[0] = cx; o[1] = cy; o[2] = cz;
        }

        float best = -1.0f;
        int   bp   = 0;
#pragma unroll
        for (int p = 0; p < PPT; ++p) {
            const float dx = __fsub_rn(px[p], cx);
            const float dy = __fsub_rn(py[p], cy);
            const float dz = __fsub_rn(pz[p], cz);
            const float d  = __fadd_rn(__fadd_rn(__fmul_rn(dx, dx),
                                                 __fmul_rn(dy, dy)),
                                       __fmul_rn(dz, dz));
            const float nd = fminf(dist[p], d);
            dist[p] = nd;
            // ascending global index in p, strict '>' => lowest index on tie
            if (nd > best) { best = nd; bp = p; }
        }
        int bi = p0 + bp * FPS_BLOCK;

        // 64-lane butterfly argmax, tie -> lower index
#pragma unroll
        for (int off = 32; off >= 1; off >>= 1) {
            const float ov = __shfl_xor(best, off, 64);
            const int   oi = __shfl_xor(bi, off, 64);
            if (ov > best || (ov == best && oi < bi)) { best = ov; bi = oi; }
        }
        if (lane == 0) { s_wval[wave] = best; s_widx[wave] = bi; }
        __syncthreads();

        if (tid == 0) {
            float v  = s_wval[0];
            int   vi = s_widx[0];
#pragma unroll
            for (int w = 1; w < FPS_BLOCK / 64; ++w) {
                const float ov = s_wval[w];
                const int   oi = s_widx[w];
                if (ov > v || (ov == v && oi < vi)) { v = ov; vi = oi; }
            }
            const unsigned long long key =
                ((unsigned long long)__float_as_uint(v) << 32) |
                (unsigned long long)(~(unsigned)vi);
            atomicMax(&mykey[s], key);
            __hip_atomic_fetch_add(&mycnt[s], 1u, __ATOMIC_ACQ_REL,
                                   __HIP_MEMORY_SCOPE_AGENT);
            while (__hip_atomic_load(&mycnt[s], __ATOMIC_ACQUIRE,
                                     __HIP_MEMORY_SCOPE_AGENT) < NBLK)
                __builtin_amdgcn_s_sleep(8);
            const unsigned long long fin =
                __hip_atomic_load(&mykey[s], __ATOMIC_RELAXED,
                                  __HIP_MEMORY_SCOPE_AGENT);
            const int vw = (int)(~(unsigned)(fin & 0xFFFFFFFFull));
            s_fidx = vw;
            s_cx = base[vw * 3 + 0];
            s_cy = base[vw * 3 + 1];
            s_cz = base[vw * 3 + 2];
        }
        __syncthreads();
        cur = s_fidx;
        cx = s_cx; cy = s_cy; cz = s_cz;
    }
}

// ---------------------------------------------------------------------------
// Kernel 2: gather selected rows, 1x1 conv (x @ W + b), ReLU.
// ---------------------------------------------------------------------------
#define SAMP_PER_BLK 16

__global__ __launch_bounds__(256)
void gather_linear_relu_kernel(const float* __restrict__ xyz,    // [B,N,3]
                               const float* __restrict__ feats,  // [B,N,F]
                               const int* __restrict__ idx,      // [B*S]
                               const float* __restrict__ W,      // [67,128]
                               const float* __restrict__ bias,   // [128]
                               float* __restrict__ out)          // [B*S,128]
{
    __shared__ float sW[C_IN][D_OUT];
    __shared__ float sX[SAMP_PER_BLK][C_IN + 1];
    __shared__ float sB[D_OUT];

    const int tid = threadIdx.x;

    for (int i = tid; i < C_IN * D_OUT; i += 256)
        (&sW[0][0])[i] = W[i];
    if (tid < D_OUT) sB[tid] = bias[tid];

    const int gs0 = blockIdx.x * SAMP_PER_BLK;

    {
        const int si = tid >> 4;
        const int j  = tid & 15;
        const int gs = gs0 + si;
        const int bb = gs >> 11;
        const int pt = idx[gs];
        const float* frow = feats + ((size_t)bb * NPTS + pt) * F_IN;
        const float* xrow = xyz   + ((size_t)bb * NPTS + pt) * 3;
        for (int c = j; c < F_IN; c += 16) sX[si][c] = frow[c];
        if (j < 3) sX[si][F_IN + j] = xrow[j];
    }
    __syncthreads();

    const int d = tid & 127;
    const int g = tid >> 7;
    float acc[8];
#pragma unroll
    for (int k = 0; k < 8; ++k) acc[k] = 0.0f;

    for (int c = 0; c < C_IN; ++c) {
        const float w = sW[c][d];
#pragma unroll
        for (int k = 0; k < 8; ++k)
            acc[k] = fmaf(sX[g * 8 + k][c], w, acc[k]);
    }

    const float bv = sB[d];
#pragma unroll
    for (int k = 0; k < 8; ++k) {
        const int gs = gs0 + g * 8 + k;
        const float v = acc[k] + bv;
        out[(size_t)gs * D_OUT + d] = fmaxf(v, 0.0f);
    }
}

// ---------------------------------------------------------------------------
extern "C" void kernel_launch(void* const* d_in, const int* in_sizes, int n_in,
                              void* d_out, int out_size, void* d_ws, size_t ws_size,
                              hipStream_t stream) {
    const float* xyz      = (const float*)d_in[0];
    const float* feats    = (const float*)d_in[1];
    const int*   init_far = (const int*)d_in[2];
    const float* W        = (const float*)d_in[3];
    const float* bias     = (const float*)d_in[4];

    float* out_newxyz = (float*)d_out;
    float* out_conv   = (float*)d_out + (size_t)B_SZ * NSAMP * 3;

    // ws layout: idx [B*S] i32 | gkey [B*S] u64 | gcnt [B*S] u32
    char* ws = (char*)d_ws;
    int*                idx_ws = (int*)ws;
    unsigned long long* gkey   = (unsigned long long*)(ws + (size_t)B_SZ * NSAMP * 4);
    unsigned int*       gcnt   = (unsigned int*)(ws + (size_t)B_SZ * NSAMP * 12);

    // zero the sync structures every call (graph-capture-safe)
    hipMemsetAsync(gkey, 0, (size_t)B_SZ * NSAMP * 12, stream);

    fps_kernel<<<B_SZ * NBLK, FPS_BLOCK, 0, stream>>>(
        xyz, init_far, idx_ws, out_newxyz, gkey, gcnt);

    const int nblocks = (B_SZ * NSAMP) / SAMP_PER_BLK;
    gather_linear_relu_kernel<<<nblocks, 256, 0, stream>>>(
        xyz, feats, idx_ws, W, bias, out_conv);
}

// Round 4
// 3616.412 us; speedup vs baseline: 3.9661x; 3.9661x over previous
//
#include <hip/hip_runtime.h>
#include <cstdint>
#include <cstddef>

#define B_SZ 32
#define NPTS 16384
#define NSAMP 2048
#define F_IN 64
#define C_IN 67
#define D_OUT 128
#define FPS_THREADS 512
#define PPT 32                  // points per thread
#define NWAVE (FPS_THREADS / 64)

// ---------------------------------------------------------------------------
// FPS: one block per batch, 512 threads, 32 points/thread in registers.
// Per iteration (ONE barrier):
//   1. dist update + per-thread argmax (explicit rn ops, no FMA -> bit-match)
//   2. wave butterfly on packed u64 key (dist_bits<<32 | ~idx):
//      max key == max dist, tie -> lowest index  (== jnp.argmax)
//   3. lane0 writes key to LDS slot [parity][wave]
//   4. __syncthreads()
//   5. ALL threads redundantly reduce the 8 keys -> vi (identical result),
//      load centroid xyz[vi] (broadcast, L2-hit) -- concurrent, not serial.
// Ping-pong key slots by iteration parity => single barrier is race-free.
// ---------------------------------------------------------------------------
__global__ __launch_bounds__(FPS_THREADS, 2)
void fps_kernel(const float* __restrict__ xyz,       // [B, N, 3]
                const int* __restrict__ init_far,    // [B]
                int* __restrict__ idx_out,           // [B, S]
                float* __restrict__ newxyz_out)      // [B, S, 3]
{
    const int b = blockIdx.x;
    const int tid = threadIdx.x;
    const float* base = xyz + (size_t)b * NPTS * 3;

    float px[PPT], py[PPT], pz[PPT], dist[PPT];
#pragma unroll
    for (int p = 0; p < PPT; ++p) {
        const int i = tid + p * FPS_THREADS;     // ascending in p
        px[p] = base[i * 3 + 0];
        py[p] = base[i * 3 + 1];
        pz[p] = base[i * 3 + 2];
        dist[p] = 1e10f;
    }

    __shared__ unsigned long long s_key[2][NWAVE];

    // initial centroid: uniform broadcast
    int cur = init_far[b];
    float cx = base[cur * 3 + 0];
    float cy = base[cur * 3 + 1];
    float cz = base[cur * 3 + 2];

    const int lane = tid & 63;
    const int wave = tid >> 6;

    for (int s = 0; s < NSAMP; ++s) {
        // record BEFORE update (reference scan semantics); fire-and-forget
        if (tid == 0) {
            idx_out[b * NSAMP + s] = cur;
            float* o = newxyz_out + (size_t)(b * NSAMP + s) * 3;
            o[0] = cx; o[1] = cy; o[2] = cz;
        }

        float best = -1.0f;
        int   bp   = 0;
#pragma unroll
        for (int p = 0; p < PPT; ++p) {
            const float dx = __fsub_rn(px[p], cx);
            const float dy = __fsub_rn(py[p], cy);
            const float dz = __fsub_rn(pz[p], cz);
            const float d  = __fadd_rn(__fadd_rn(__fmul_rn(dx, dx),
                                                 __fmul_rn(dy, dy)),
                                       __fmul_rn(dz, dz));
            const float nd = fminf(dist[p], d);
            dist[p] = nd;
            // ascending global index in p, strict '>' => lowest index on tie
            if (nd > best) { best = nd; bp = p; }
        }
        const int bi = tid + bp * FPS_THREADS;

        // packed key: max dist wins; tie -> lowest index (~bi is larger)
        unsigned long long key =
            ((unsigned long long)__float_as_uint(best) << 32) |
            (unsigned long long)(~(unsigned)bi);

        // 64-lane butterfly max on the u64 key
#pragma unroll
        for (int off = 32; off >= 1; off >>= 1) {
            const unsigned lo = (unsigned)key;
            const unsigned hi = (unsigned)(key >> 32);
            const unsigned olo = (unsigned)__shfl_xor((int)lo, off, 64);
            const unsigned ohi = (unsigned)__shfl_xor((int)hi, off, 64);
            const unsigned long long ok =
                ((unsigned long long)ohi << 32) | (unsigned long long)olo;
            key = (ok > key) ? ok : key;
        }
        if (lane == 0) s_key[s & 1][wave] = key;
        __syncthreads();

        // all threads redundantly reduce the 8 wave keys
        unsigned long long fin = s_key[s & 1][0];
#pragma unroll
        for (int w = 1; w < NWAVE; ++w) {
            const unsigned long long k = s_key[s & 1][w];
            fin = (k > fin) ? k : fin;
        }
        const int vi = (int)(~(unsigned)(fin & 0xFFFFFFFFull));
        cur = vi;
        // broadcast centroid load (same address all lanes, L1/L2-hit)
        cx = base[vi * 3 + 0];
        cy = base[vi * 3 + 1];
        cz = base[vi * 3 + 2];
    }
}

// ---------------------------------------------------------------------------
// Kernel 2: gather selected rows, 1x1 conv (x @ W + b), ReLU.
// ---------------------------------------------------------------------------
#define SAMP_PER_BLK 16

__global__ __launch_bounds__(256)
void gather_linear_relu_kernel(const float* __restrict__ xyz,    // [B,N,3]
                               const float* __restrict__ feats,  // [B,N,F]
                               const int* __restrict__ idx,      // [B*S]
                               const float* __restrict__ W,      // [67,128]
                               const float* __restrict__ bias,   // [128]
                               float* __restrict__ out)          // [B*S,128]
{
    __shared__ float sW[C_IN][D_OUT];
    __shared__ float sX[SAMP_PER_BLK][C_IN + 1];
    __shared__ float sB[D_OUT];

    const int tid = threadIdx.x;

    for (int i = tid; i < C_IN * D_OUT; i += 256)
        (&sW[0][0])[i] = W[i];
    if (tid < D_OUT) sB[tid] = bias[tid];

    const int gs0 = blockIdx.x * SAMP_PER_BLK;

    {
        const int si = tid >> 4;
        const int j  = tid & 15;
        const int gs = gs0 + si;
        const int bb = gs >> 11;
        const int pt = idx[gs];
        const float* frow = feats + ((size_t)bb * NPTS + pt) * F_IN;
        const float* xrow = xyz   + ((size_t)bb * NPTS + pt) * 3;
        for (int c = j; c < F_IN; c += 16) sX[si][c] = frow[c];
        if (j < 3) sX[si][F_IN + j] = xrow[j];
    }
    __syncthreads();

    const int d = tid & 127;
    const int g = tid >> 7;
    float acc[8];
#pragma unroll
    for (int k = 0; k < 8; ++k) acc[k] = 0.0f;

    for (int c = 0; c < C_IN; ++c) {
        const float w = sW[c][d];
#pragma unroll
        for (int k = 0; k < 8; ++k)
            acc[k] = fmaf(sX[g * 8 + k][c], w, acc[k]);
    }

    const float bv = sB[d];
#pragma unroll
    for (int k = 0; k < 8; ++k) {
        const int gs = gs0 + g * 8 + k;
        const float v = acc[k] + bv;
        out[(size_t)gs * D_OUT + d] = fmaxf(v, 0.0f);
    }
}

// ---------------------------------------------------------------------------
extern "C" void kernel_launch(void* const* d_in, const int* in_sizes, int n_in,
                              void* d_out, int out_size, void* d_ws, size_t ws_size,
                              hipStream_t stream) {
    const float* xyz      = (const float*)d_in[0];
    const float* feats    = (const float*)d_in[1];
    const int*   init_far = (const int*)d_in[2];
    const float* W        = (const float*)d_in[3];
    const float* bias     = (const float*)d_in[4];

    float* out_newxyz = (float*)d_out;
    float* out_conv   = (float*)d_out + (size_t)B_SZ * NSAMP * 3;
    int*   idx_ws     = (int*)d_ws;

    fps_kernel<<<B_SZ, FPS_THREADS, 0, stream>>>(xyz, init_far, idx_ws, out_newxyz);

    const int nblocks = (B_SZ * NSAMP) / SAMP_PER_BLK;
    gather_linear_relu_kernel<<<nblocks, 256, 0, stream>>>(
        xyz, feats, idx_ws, W, bias, out_conv);
}